// Round 1
// baseline (641.203 us; speedup 1.0000x reference)
//
#include <hip/hip_runtime.h>
#include <math.h>

#define HH 512
#define WW 512
#define NCH 48
#define HWPIX (HH * WW)

// ---------------------------------------------------------------------------
// Kernel 1: precompute the 9 per-pixel stencil weights from Dt.
// Dt layout: (H, W, 3) with channels (a, c, b). Rolls are PERIODIC (jnp.roll).
// A stored as 9 planes of HW floats for coalesced reads: A[k*HW + pix].
// A[k] multiplies x[h-1+k/3, w-1+k%3] (row-major patch order, no flip).
// ---------------------------------------------------------------------------
__global__ __launch_bounds__(256) void compute_A_kernel(
    const float* __restrict__ Dt, float* __restrict__ A) {
  int pix = blockIdx.x * blockDim.x + threadIdx.x;
  int h = pix >> 9;
  int w = pix & (WW - 1);
  int hm = (h == 0) ? HH - 1 : h - 1;
  int hp = (h == HH - 1) ? 0 : h + 1;
  int wm = (w == 0) ? WW - 1 : w - 1;
  int wp = (w == WW - 1) ? 0 : w + 1;

  float aC, cC, bC, aL, cL, bL, aR, cR, bR, aU, cU, bU, aD, cD, bD;
  float bUL, bUR, bDL, bDR;
  {
    int p;
    p = (h * WW + w) * 3;   aC = Dt[p]; cC = Dt[p + 1]; bC = Dt[p + 2];
    p = (h * WW + wm) * 3;  aL = Dt[p]; cL = Dt[p + 1]; bL = Dt[p + 2];
    p = (h * WW + wp) * 3;  aR = Dt[p]; cR = Dt[p + 1]; bR = Dt[p + 2];
    p = (hm * WW + w) * 3;  aU = Dt[p]; cU = Dt[p + 1]; bU = Dt[p + 2];
    p = (hp * WW + w) * 3;  aD = Dt[p]; cD = Dt[p + 1]; bD = Dt[p + 2];
    p = (hm * WW + wm) * 3; bUL = Dt[p + 2];
    p = (hm * WW + wp) * 3; bUR = Dt[p + 2];
    p = (hp * WW + wm) * 3; bDL = Dt[p + 2];
    p = (hp * WW + wp) * 3; bDR = Dt[p + 2];
  }
  (void)cU; (void)cD; (void)aL; (void)aR;

  float A0 = (fabsf(bDL) - bDL + fabsf(bC) - bC) * 0.25f;
  float A1 = (cL + cC - fabsf(bL) - fabsf(bC)) * 0.5f;
  float A2 = (fabsf(bUL) + bUL + fabsf(bC) + bC) * 0.25f;
  float A3 = (aD + aC - fabsf(bD) - fabsf(bC)) * 0.5f;
  float A4 = -(aD + 2.f * aC + aU) * 0.5f
             - (fabsf(bDL) - bDL + fabsf(bUL) + bUL) * 0.25f
             - (fabsf(bDR) + bDR + fabsf(bUR) - bUR) * 0.25f
             + (fabsf(bD) + fabsf(bU) + fabsf(bR) + fabsf(bL) + 2.f * fabsf(bC)) * 0.5f
             - (cR + 2.f * cC + cL) * 0.5f;
  float A5 = (aU + aC - fabsf(bU) - fabsf(bC)) * 0.5f;
  float A6 = (fabsf(bDR) + bDR + fabsf(bC) + bC) * 0.25f;
  float A7 = (cR + cC - fabsf(bR) - fabsf(bC)) * 0.5f;
  float A8 = (fabsf(bUR) - bUR + fabsf(bC) - bC) * 0.25f;

  A[0 * HWPIX + pix] = A0;
  A[1 * HWPIX + pix] = A1;
  A[2 * HWPIX + pix] = A2;
  A[3 * HWPIX + pix] = A3;
  A[4 * HWPIX + pix] = A4;
  A[5 * HWPIX + pix] = A5;
  A[6 * HWPIX + pix] = A6;
  A[7 * HWPIX + pix] = A7;
  A[8 * HWPIX + pix] = A8;
}

// ---------------------------------------------------------------------------
// Kernel 2: per-pixel logsumexp over the 48 channels.
// ---------------------------------------------------------------------------
__global__ __launch_bounds__(256) void lse_kernel(
    const float* __restrict__ x, float* __restrict__ lse) {
  int pix = blockIdx.x * blockDim.x + threadIdx.x;
  const float4* xp = (const float4*)(x + (size_t)pix * NCH);
  float4 v[12];
  float m = -INFINITY;
#pragma unroll
  for (int j = 0; j < 12; j++) {
    v[j] = xp[j];
    m = fmaxf(m, fmaxf(fmaxf(v[j].x, v[j].y), fmaxf(v[j].z, v[j].w)));
  }
  float s = 0.f;
#pragma unroll
  for (int j = 0; j < 12; j++) {
    s += __expf(v[j].x - m) + __expf(v[j].y - m) +
         __expf(v[j].z - m) + __expf(v[j].w - m);
  }
  lse[pix] = m + __logf(s);
}

// ---------------------------------------------------------------------------
// Kernel 3: one Euler step.  x_next = x + 0.2 * clip(Pi_0(val), +-1e8)
//   val = stencil(x)/dg + 0.5*(ha*v0^2 + hc*v1^2) + hb*v0*v1 + 0.1*x
//   v0 = logp[h+1,w]-logp[h,w] (periodic), v1 = logp[h,w+1]-logp[h,w]
// Stencil is ZERO-padded: implemented as wrapped loads with masked weights.
// ---------------------------------------------------------------------------
__global__ __launch_bounds__(256) void step_kernel(
    const float* __restrict__ x, const float* __restrict__ lse,
    const float* __restrict__ A, const float* __restrict__ dg,
    const float* __restrict__ hinv, float* __restrict__ xn) {
  int pix = blockIdx.x * blockDim.x + threadIdx.x;
  int h = pix >> 9;
  int w = pix & (WW - 1);
  int hm = (h == 0) ? HH - 1 : h - 1;
  int hp = (h == HH - 1) ? 0 : h + 1;
  int wm = (w == 0) ? WW - 1 : w - 1;
  int wp = (w == WW - 1) ? 0 : w + 1;

  float wt[9];
#pragma unroll
  for (int k = 0; k < 9; k++) wt[k] = A[k * HWPIX + pix];
  // zero-padding of the conv: drop out-of-bounds contributions
  bool ru = (h > 0), rd = (h < HH - 1), cl = (w > 0), cr = (w < WW - 1);
  if (!(ru && cl)) wt[0] = 0.f;
  if (!ru)         wt[1] = 0.f;
  if (!(ru && cr)) wt[2] = 0.f;
  if (!cl)         wt[3] = 0.f;
  if (!cr)         wt[5] = 0.f;
  if (!(rd && cl)) wt[6] = 0.f;
  if (!rd)         wt[7] = 0.f;
  if (!(rd && cr)) wt[8] = 0.f;

  float invdg = 1.0f / dg[pix];
  float ha = hinv[pix * 3 + 0];
  float hc = hinv[pix * 3 + 1];
  float hb = hinv[pix * 3 + 2];
  float lc = lse[pix];
  float dld = lc - lse[hp * WW + w];   // lse[h,w] - lse[h+1,w]
  float dlr = lc - lse[h * WW + wp];   // lse[h,w] - lse[h,w+1]

  const float4* p[9];
  {
    int rows[3] = {hm, h, hp};
    int cols[3] = {wm, w, wp};
#pragma unroll
    for (int r = 0; r < 3; r++)
#pragma unroll
      for (int c = 0; c < 3; c++)
        p[r * 3 + c] = (const float4*)(x + (size_t)(rows[r] * WW + cols[c]) * NCH);
  }

  float4 vals[12];
  float sum = 0.f;
#pragma unroll
  for (int j = 0; j < 12; j++) {
    float4 n0 = p[0][j], n1 = p[1][j], n2 = p[2][j];
    float4 n3 = p[3][j], n4 = p[4][j], n5 = p[5][j];
    float4 n6 = p[6][j], n7 = p[7][j], n8 = p[8][j];
    float4 val;
#define COMP(f)                                                              \
    {                                                                        \
      float s_ = wt[0] * n0.f + wt[1] * n1.f + wt[2] * n2.f + wt[3] * n3.f + \
                 wt[4] * n4.f + wt[5] * n5.f + wt[6] * n6.f + wt[7] * n7.f + \
                 wt[8] * n8.f;                                               \
      float v0_ = n7.f - n4.f + dld;                                         \
      float v1_ = n5.f - n4.f + dlr;                                         \
      float vv = s_ * invdg + 0.5f * (ha * v0_ * v0_ + hc * v1_ * v1_) +     \
                 hb * (v0_ * v1_) + 0.1f * n4.f;                             \
      val.f = vv;                                                            \
      sum += vv;                                                             \
    }
    COMP(x) COMP(y) COMP(z) COMP(w)
#undef COMP
    vals[j] = val;
  }

  float mean = sum * (1.0f / 48.0f);
  const float4* cp = p[4];
  float4* op = (float4*)(xn + (size_t)pix * NCH);
#pragma unroll
  for (int j = 0; j < 12; j++) {
    float4 c4 = cp[j];
    float4 r;
    r.x = c4.x + 0.2f * fminf(fmaxf(vals[j].x - mean, -1e8f), 1e8f);
    r.y = c4.y + 0.2f * fminf(fmaxf(vals[j].y - mean, -1e8f), 1e8f);
    r.z = c4.z + 0.2f * fminf(fmaxf(vals[j].z - mean, -1e8f), 1e8f);
    r.w = c4.w + 0.2f * fminf(fmaxf(vals[j].w - mean, -1e8f), 1e8f);
    op[j] = r;
  }
}

// ---------------------------------------------------------------------------
// Host launcher.  inputs: v (H,W,48), Dt (H,W,3), dg (H,W,1), hinv (H,W,3)
// ws layout: A[9*HW] | lse[HW] | xbuf[HW*48]   (~61 MB)
// ping-pong: v -> out -> ws -> out -> ws -> out  (5 steps)
// ---------------------------------------------------------------------------
extern "C" void kernel_launch(void* const* d_in, const int* in_sizes, int n_in,
                              void* d_out, int out_size, void* d_ws, size_t ws_size,
                              hipStream_t stream) {
  const float* v    = (const float*)d_in[0];
  const float* Dt   = (const float*)d_in[1];
  const float* dg   = (const float*)d_in[2];
  const float* hinv = (const float*)d_in[3];
  float* out = (float*)d_out;

  float* A    = (float*)d_ws;
  float* lse  = A + 9 * (size_t)HWPIX;
  float* xbuf = lse + (size_t)HWPIX;

  dim3 blk(256), grd(HWPIX / 256);
  compute_A_kernel<<<grd, blk, 0, stream>>>(Dt, A);

  const float* cur = v;
  float* nxt = out;
  for (int s = 0; s < 5; s++) {
    lse_kernel<<<grd, blk, 0, stream>>>(cur, lse);
    step_kernel<<<grd, blk, 0, stream>>>(cur, lse, A, dg, hinv, nxt);
    if (s == 0) {
      cur = out;
      nxt = xbuf;
    } else {
      float* t = (float*)cur;
      cur = nxt;
      nxt = t;
    }
  }
}

// Round 2
// 584.974 us; speedup vs baseline: 1.0961x; 1.0961x over previous
//
#include <hip/hip_runtime.h>
#include <math.h>

#define HH 512
#define WW 512
#define NCH 48
#define HWPIX (HH * WW)

// ---------------------------------------------------------------------------
// Kernel 1: precompute the 9 per-pixel stencil weights from Dt, with
//   - border zero-padding masks folded in (conv is SAME/zero-pad),
//   - 1/dg folded in (val = stencil(x)/dg),
//   - MSQ = 0.1 folded into the center weight (0.1*x term).
// Dt layout: (H, W, 3) with channels (a, c, b). Rolls are PERIODIC (jnp.roll).
// A stored as 9 planes of HW floats: A[k*HW + pix], A[k] multiplies
// x[h-1+k/3, w-1+k%3] (row-major patch order, no flip).
// ---------------------------------------------------------------------------
__global__ __launch_bounds__(256) void compute_A_kernel(
    const float* __restrict__ Dt, const float* __restrict__ dg,
    float* __restrict__ A) {
  int pix = blockIdx.x * blockDim.x + threadIdx.x;
  int h = pix >> 9;
  int w = pix & (WW - 1);
  int hm = (h == 0) ? HH - 1 : h - 1;
  int hp = (h == HH - 1) ? 0 : h + 1;
  int wm = (w == 0) ? WW - 1 : w - 1;
  int wp = (w == WW - 1) ? 0 : w + 1;

  float aC, cC, bC, cL, bL, cR, bR, aU, bU, aD, bD;
  float bUL, bUR, bDL, bDR;
  {
    int p;
    p = (h * WW + w) * 3;   aC = Dt[p]; cC = Dt[p + 1]; bC = Dt[p + 2];
    p = (h * WW + wm) * 3;  cL = Dt[p + 1]; bL = Dt[p + 2];
    p = (h * WW + wp) * 3;  cR = Dt[p + 1]; bR = Dt[p + 2];
    p = (hm * WW + w) * 3;  aU = Dt[p]; bU = Dt[p + 2];
    p = (hp * WW + w) * 3;  aD = Dt[p]; bD = Dt[p + 2];
    p = (hm * WW + wm) * 3; bUL = Dt[p + 2];
    p = (hm * WW + wp) * 3; bUR = Dt[p + 2];
    p = (hp * WW + wm) * 3; bDL = Dt[p + 2];
    p = (hp * WW + wp) * 3; bDR = Dt[p + 2];
  }

  float A0 = (fabsf(bDL) - bDL + fabsf(bC) - bC) * 0.25f;
  float A1 = (cL + cC - fabsf(bL) - fabsf(bC)) * 0.5f;
  float A2 = (fabsf(bUL) + bUL + fabsf(bC) + bC) * 0.25f;
  float A3 = (aD + aC - fabsf(bD) - fabsf(bC)) * 0.5f;
  float A4 = -(aD + 2.f * aC + aU) * 0.5f
             - (fabsf(bDL) - bDL + fabsf(bUL) + bUL) * 0.25f
             - (fabsf(bDR) + bDR + fabsf(bUR) - bUR) * 0.25f
             + (fabsf(bD) + fabsf(bU) + fabsf(bR) + fabsf(bL) + 2.f * fabsf(bC)) * 0.5f
             - (cR + 2.f * cC + cL) * 0.5f;
  float A5 = (aU + aC - fabsf(bU) - fabsf(bC)) * 0.5f;
  float A6 = (fabsf(bDR) + bDR + fabsf(bC) + bC) * 0.25f;
  float A7 = (cR + cC - fabsf(bR) - fabsf(bC)) * 0.5f;
  float A8 = (fabsf(bUR) - bUR + fabsf(bC) - bC) * 0.25f;

  // zero-padding of the conv: drop out-of-bounds contributions
  bool ru = (h > 0), rd = (h < HH - 1), cl = (w > 0), cr = (w < WW - 1);
  if (!(ru && cl)) A0 = 0.f;
  if (!ru)         A1 = 0.f;
  if (!(ru && cr)) A2 = 0.f;
  if (!cl)         A3 = 0.f;
  if (!cr)         A5 = 0.f;
  if (!(rd && cl)) A6 = 0.f;
  if (!rd)         A7 = 0.f;
  if (!(rd && cr)) A8 = 0.f;

  float invdg = 1.0f / dg[pix];
  A[0 * HWPIX + pix] = A0 * invdg;
  A[1 * HWPIX + pix] = A1 * invdg;
  A[2 * HWPIX + pix] = A2 * invdg;
  A[3 * HWPIX + pix] = A3 * invdg;
  A[4 * HWPIX + pix] = A4 * invdg + 0.1f;   // + MSQ*x folded into center tap
  A[5 * HWPIX + pix] = A5 * invdg;
  A[6 * HWPIX + pix] = A6 * invdg;
  A[7 * HWPIX + pix] = A7 * invdg;
  A[8 * HWPIX + pix] = A8 * invdg;
}

// XCD-band swizzle: 1024 half-row blocks; assuming round-robin block->XCD
// dispatch (b % 8), give XCD k the contiguous row band [64k, 64k+64) so each
// row's 98 KB is fetched into exactly one per-XCD L2 and reused by the ±1-row
// neighbors (reuse distance ±2 blocks).
__device__ __forceinline__ int swizzled_pix() {
  int b = blockIdx.x;
  int p = (b & 7) * 128 + (b >> 3);
  return p * 256 + threadIdx.x;
}

// ---------------------------------------------------------------------------
// Kernel 2: per-pixel logsumexp over the 48 channels.
// ---------------------------------------------------------------------------
__global__ __launch_bounds__(256) void lse_kernel(
    const float* __restrict__ x, float* __restrict__ lse) {
  int pix = swizzled_pix();
  const float4* xp = (const float4*)(x + (size_t)pix * NCH);
  float4 v[12];
  float m = -INFINITY;
#pragma unroll
  for (int j = 0; j < 12; j++) {
    v[j] = xp[j];
    m = fmaxf(m, fmaxf(fmaxf(v[j].x, v[j].y), fmaxf(v[j].z, v[j].w)));
  }
  float s = 0.f;
#pragma unroll
  for (int j = 0; j < 12; j++) {
    s += __expf(v[j].x - m) + __expf(v[j].y - m) +
         __expf(v[j].z - m) + __expf(v[j].w - m);
  }
  lse[pix] = m + __logf(s);
}

// ---------------------------------------------------------------------------
// Kernel 3: one Euler step.  x_next = x + 0.2 * clip(Pi_0(val), +-1e8)
//   val = sum_k Aeff[k]*x[nbr_k] + 0.5*(ha*v0^2 + hc*v1^2) + hb*v0*v1
//   (1/dg, border masks, and 0.1*x already folded into Aeff)
//   v0 = logp[h+1,w]-logp[h,w] (periodic), v1 = logp[h,w+1]-logp[h,w]
// ---------------------------------------------------------------------------
__global__ __launch_bounds__(256) void step_kernel(
    const float* __restrict__ x, const float* __restrict__ lse,
    const float* __restrict__ A,
    const float* __restrict__ hinv, float* __restrict__ xn) {
  int pix = swizzled_pix();
  int h = pix >> 9;
  int w = pix & (WW - 1);
  int hm = (h == 0) ? HH - 1 : h - 1;
  int hp = (h == HH - 1) ? 0 : h + 1;
  int wm = (w == 0) ? WW - 1 : w - 1;
  int wp = (w == WW - 1) ? 0 : w + 1;

  float wt[9];
#pragma unroll
  for (int k = 0; k < 9; k++) wt[k] = A[k * HWPIX + pix];

  float ha = hinv[pix * 3 + 0];
  float hc = hinv[pix * 3 + 1];
  float hb = hinv[pix * 3 + 2];
  float lc = lse[pix];
  float dld = lc - lse[hp * WW + w];   // lse[h,w] - lse[h+1,w]
  float dlr = lc - lse[h * WW + wp];   // lse[h,w] - lse[h,w+1]

  const float4* p[9];
  {
    int rows[3] = {hm, h, hp};
    int cols[3] = {wm, w, wp};
#pragma unroll
    for (int r = 0; r < 3; r++)
#pragma unroll
      for (int c = 0; c < 3; c++)
        p[r * 3 + c] = (const float4*)(x + (size_t)(rows[r] * WW + cols[c]) * NCH);
  }

  float4 vals[12];
  float sum = 0.f;
#pragma unroll
  for (int j = 0; j < 12; j++) {
    float4 n0 = p[0][j], n1 = p[1][j], n2 = p[2][j];
    float4 n3 = p[3][j], n4 = p[4][j], n5 = p[5][j];
    float4 n6 = p[6][j], n7 = p[7][j], n8 = p[8][j];
    float4 val;
#define COMP(f)                                                              \
    {                                                                        \
      float s_ = wt[0] * n0.f + wt[1] * n1.f + wt[2] * n2.f + wt[3] * n3.f + \
                 wt[4] * n4.f + wt[5] * n5.f + wt[6] * n6.f + wt[7] * n7.f + \
                 wt[8] * n8.f;                                               \
      float v0_ = n7.f - n4.f + dld;                                         \
      float v1_ = n5.f - n4.f + dlr;                                         \
      float vv = s_ + 0.5f * (ha * v0_ * v0_ + hc * v1_ * v1_) +             \
                 hb * (v0_ * v1_);                                           \
      val.f = vv;                                                            \
      sum += vv;                                                             \
    }
    COMP(x) COMP(y) COMP(z) COMP(w)
#undef COMP
    vals[j] = val;
  }

  float mean = sum * (1.0f / 48.0f);
  const float4* cp = p[4];
  float4* op = (float4*)(xn + (size_t)pix * NCH);
#pragma unroll
  for (int j = 0; j < 12; j++) {
    float4 c4 = cp[j];
    float4 r;
    r.x = c4.x + 0.2f * fminf(fmaxf(vals[j].x - mean, -1e8f), 1e8f);
    r.y = c4.y + 0.2f * fminf(fmaxf(vals[j].y - mean, -1e8f), 1e8f);
    r.z = c4.z + 0.2f * fminf(fmaxf(vals[j].z - mean, -1e8f), 1e8f);
    r.w = c4.w + 0.2f * fminf(fmaxf(vals[j].w - mean, -1e8f), 1e8f);
    op[j] = r;
  }
}

// ---------------------------------------------------------------------------
// Host launcher.  inputs: v (H,W,48), Dt (H,W,3), dg (H,W,1), hinv (H,W,3)
// ws layout: A[9*HW] | lse[HW] | xbuf[HW*48]   (~61 MB)
// ping-pong: v -> out -> ws -> out -> ws -> out  (5 steps)
// ---------------------------------------------------------------------------
extern "C" void kernel_launch(void* const* d_in, const int* in_sizes, int n_in,
                              void* d_out, int out_size, void* d_ws, size_t ws_size,
                              hipStream_t stream) {
  const float* v    = (const float*)d_in[0];
  const float* Dt   = (const float*)d_in[1];
  const float* dg   = (const float*)d_in[2];
  const float* hinv = (const float*)d_in[3];
  float* out = (float*)d_out;

  float* A    = (float*)d_ws;
  float* lse  = A + 9 * (size_t)HWPIX;
  float* xbuf = lse + (size_t)HWPIX;

  dim3 blk(256), grd(HWPIX / 256);
  compute_A_kernel<<<grd, blk, 0, stream>>>(Dt, dg, A);

  const float* cur = v;
  float* nxt = out;
  for (int s = 0; s < 5; s++) {
    lse_kernel<<<grd, blk, 0, stream>>>(cur, lse);
    step_kernel<<<grd, blk, 0, stream>>>(cur, lse, A, hinv, nxt);
    if (s == 0) {
      cur = out;
      nxt = xbuf;
    } else {
      float* t = (float*)cur;
      cur = nxt;
      nxt = t;
    }
  }
}

// Round 3
// 276.894 us; speedup vs baseline: 2.3157x; 2.1126x over previous
//
#include <hip/hip_runtime.h>
#include <math.h>

#define HH 512
#define WW 512
#define NCH 48
#define HWPIX (HH * WW)

// ---------------------------------------------------------------------------
// Kernel 1: precompute the 9 per-pixel stencil weights from Dt, with
//   - border zero-padding masks folded in (conv is SAME/zero-pad),
//   - 1/dg folded in (val = stencil(x)/dg),
//   - MSQ = 0.1 folded into the center weight (0.1*x term).
// Dt layout: (H, W, 3) with channels (a, c, b). Rolls are PERIODIC (jnp.roll).
// A stored as 9 planes of HW floats: A[k*HW + pix], A[k] multiplies
// x[h-1+k/3, w-1+k%3] (row-major patch order, no flip).
// ---------------------------------------------------------------------------
__global__ __launch_bounds__(256) void compute_A_kernel(
    const float* __restrict__ Dt, const float* __restrict__ dg,
    float* __restrict__ A) {
  int pix = blockIdx.x * blockDim.x + threadIdx.x;
  int h = pix >> 9;
  int w = pix & (WW - 1);
  int hm = (h == 0) ? HH - 1 : h - 1;
  int hp = (h == HH - 1) ? 0 : h + 1;
  int wm = (w == 0) ? WW - 1 : w - 1;
  int wp = (w == WW - 1) ? 0 : w + 1;

  float aC, cC, bC, cL, bL, cR, bR, aU, bU, aD, bD;
  float bUL, bUR, bDL, bDR;
  {
    int p;
    p = (h * WW + w) * 3;   aC = Dt[p]; cC = Dt[p + 1]; bC = Dt[p + 2];
    p = (h * WW + wm) * 3;  cL = Dt[p + 1]; bL = Dt[p + 2];
    p = (h * WW + wp) * 3;  cR = Dt[p + 1]; bR = Dt[p + 2];
    p = (hm * WW + w) * 3;  aU = Dt[p]; bU = Dt[p + 2];
    p = (hp * WW + w) * 3;  aD = Dt[p]; bD = Dt[p + 2];
    p = (hm * WW + wm) * 3; bUL = Dt[p + 2];
    p = (hm * WW + wp) * 3; bUR = Dt[p + 2];
    p = (hp * WW + wm) * 3; bDL = Dt[p + 2];
    p = (hp * WW + wp) * 3; bDR = Dt[p + 2];
  }

  float A0 = (fabsf(bDL) - bDL + fabsf(bC) - bC) * 0.25f;
  float A1 = (cL + cC - fabsf(bL) - fabsf(bC)) * 0.5f;
  float A2 = (fabsf(bUL) + bUL + fabsf(bC) + bC) * 0.25f;
  float A3 = (aD + aC - fabsf(bD) - fabsf(bC)) * 0.5f;
  float A4 = -(aD + 2.f * aC + aU) * 0.5f
             - (fabsf(bDL) - bDL + fabsf(bUL) + bUL) * 0.25f
             - (fabsf(bDR) + bDR + fabsf(bUR) - bUR) * 0.25f
             + (fabsf(bD) + fabsf(bU) + fabsf(bR) + fabsf(bL) + 2.f * fabsf(bC)) * 0.5f
             - (cR + 2.f * cC + cL) * 0.5f;
  float A5 = (aU + aC - fabsf(bU) - fabsf(bC)) * 0.5f;
  float A6 = (fabsf(bDR) + bDR + fabsf(bC) + bC) * 0.25f;
  float A7 = (cR + cC - fabsf(bR) - fabsf(bC)) * 0.5f;
  float A8 = (fabsf(bUR) - bUR + fabsf(bC) - bC) * 0.25f;

  // zero-padding of the conv: drop out-of-bounds contributions
  bool ru = (h > 0), rd = (h < HH - 1), cl = (w > 0), cr = (w < WW - 1);
  if (!(ru && cl)) A0 = 0.f;
  if (!ru)         A1 = 0.f;
  if (!(ru && cr)) A2 = 0.f;
  if (!cl)         A3 = 0.f;
  if (!cr)         A5 = 0.f;
  if (!(rd && cl)) A6 = 0.f;
  if (!rd)         A7 = 0.f;
  if (!(rd && cr)) A8 = 0.f;

  float invdg = 1.0f / dg[pix];
  A[0 * HWPIX + pix] = A0 * invdg;
  A[1 * HWPIX + pix] = A1 * invdg;
  A[2 * HWPIX + pix] = A2 * invdg;
  A[3 * HWPIX + pix] = A3 * invdg;
  A[4 * HWPIX + pix] = A4 * invdg + 0.1f;   // + MSQ*x folded into center tap
  A[5 * HWPIX + pix] = A5 * invdg;
  A[6 * HWPIX + pix] = A6 * invdg;
  A[7 * HWPIX + pix] = A7 * invdg;
  A[8 * HWPIX + pix] = A8 * invdg;
}

// ---------------------------------------------------------------------------
// Fused Euler step. 4 threads per pixel (12 channels = 3 float4 each),
// 64 pixels per 256-thread block, 4096 blocks.
// The three logsumexps needed (center, down=h+1, right=w+1) are computed
// in-register from the already-loaded neighbor vectors via 2-stage
// __shfl_xor butterflies over the 4-thread quad — no separate lse pass.
//   val = sum_k Aeff[k]*x[nbr_k] + 0.5*(ha*v0^2 + hc*v1^2) + hb*v0*v1
//   v0 = logp[h+1,w]-logp[h,w], v1 = logp[h,w+1]-logp[h,w]  (periodic)
//   x_next = x + 0.2 * clip(val - mean_ch(val), +-1e8)
// XCD-band swizzle: with 4096 blocks round-robin over 8 XCDs, give XCD k
// the contiguous 64-row band so stencil reuse stays within one per-XCD L2.
// ---------------------------------------------------------------------------
__global__ __launch_bounds__(256) void step_fused_kernel(
    const float* __restrict__ x, const float* __restrict__ A,
    const float* __restrict__ hinv, float* __restrict__ xn) {
  int b = blockIdx.x;
  int chunk = (b & 7) * 512 + (b >> 3);       // 64-pixel chunk index
  int sub = threadIdx.x & 3;                  // which 12-channel slice
  int pix = chunk * 64 + (threadIdx.x >> 2);
  int h = pix >> 9;
  int w = pix & (WW - 1);
  int hm = (h == 0) ? HH - 1 : h - 1;
  int hp = (h == HH - 1) ? 0 : h + 1;
  int wm = (w == 0) ? WW - 1 : w - 1;
  int wp = (w == WW - 1) ? 0 : w + 1;

  float wt[9];
#pragma unroll
  for (int k = 0; k < 9; k++) wt[k] = A[k * HWPIX + pix];

  float ha = hinv[pix * 3 + 0];
  float hc = hinv[pix * 3 + 1];
  float hb = hinv[pix * 3 + 2];

  // neighbor base pointers, offset to this thread's 12-channel slice
  const float4* p[9];
  {
    int rows[3] = {hm, h, hp};
    int cols[3] = {wm, w, wp};
#pragma unroll
    for (int r = 0; r < 3; r++)
#pragma unroll
      for (int c = 0; c < 3; c++)
        p[r * 3 + c] =
            (const float4*)(x + (size_t)(rows[r] * WW + cols[c]) * NCH) + sub * 3;
  }

  // load all 9 neighbors x 3 float4
  float4 n[9][3];
#pragma unroll
  for (int k = 0; k < 9; k++)
#pragma unroll
    for (int j = 0; j < 3; j++) n[k][j] = p[k][j];

  // --- logsumexp for center (n4), down (n7), right (n5) ------------------
#define TMAX4(q) fmaxf(fmaxf(q.x, q.y), fmaxf(q.z, q.w))
#define TSUM4(q, m) (__expf(q.x - m) + __expf(q.y - m) + __expf(q.z - m) + __expf(q.w - m))
  float m4 = fmaxf(TMAX4(n[4][0]), fmaxf(TMAX4(n[4][1]), TMAX4(n[4][2])));
  float m5 = fmaxf(TMAX4(n[5][0]), fmaxf(TMAX4(n[5][1]), TMAX4(n[5][2])));
  float m7 = fmaxf(TMAX4(n[7][0]), fmaxf(TMAX4(n[7][1]), TMAX4(n[7][2])));
  m4 = fmaxf(m4, __shfl_xor(m4, 1)); m4 = fmaxf(m4, __shfl_xor(m4, 2));
  m5 = fmaxf(m5, __shfl_xor(m5, 1)); m5 = fmaxf(m5, __shfl_xor(m5, 2));
  m7 = fmaxf(m7, __shfl_xor(m7, 1)); m7 = fmaxf(m7, __shfl_xor(m7, 2));
  float s4 = TSUM4(n[4][0], m4) + TSUM4(n[4][1], m4) + TSUM4(n[4][2], m4);
  float s5 = TSUM4(n[5][0], m5) + TSUM4(n[5][1], m5) + TSUM4(n[5][2], m5);
  float s7 = TSUM4(n[7][0], m7) + TSUM4(n[7][1], m7) + TSUM4(n[7][2], m7);
  s4 += __shfl_xor(s4, 1); s4 += __shfl_xor(s4, 2);
  s5 += __shfl_xor(s5, 1); s5 += __shfl_xor(s5, 2);
  s7 += __shfl_xor(s7, 1); s7 += __shfl_xor(s7, 2);
  float lse4 = m4 + __logf(s4);
  float lse5 = m5 + __logf(s5);
  float lse7 = m7 + __logf(s7);
  float dld = lse4 - lse7;   // lse[h,w] - lse[h+1,w]
  float dlr = lse4 - lse5;   // lse[h,w] - lse[h,w+1]
#undef TMAX4
#undef TSUM4

  // --- stencil + quadratic form over this thread's 12 channels ------------
  float4 vals[3];
  float sum = 0.f;
#pragma unroll
  for (int j = 0; j < 3; j++) {
    float4 val;
#define COMP(f)                                                               \
    {                                                                         \
      float s_ = wt[0] * n[0][j].f + wt[1] * n[1][j].f + wt[2] * n[2][j].f +  \
                 wt[3] * n[3][j].f + wt[4] * n[4][j].f + wt[5] * n[5][j].f +  \
                 wt[6] * n[6][j].f + wt[7] * n[7][j].f + wt[8] * n[8][j].f;   \
      float v0_ = n[7][j].f - n[4][j].f + dld;                                \
      float v1_ = n[5][j].f - n[4][j].f + dlr;                                \
      float vv = s_ + 0.5f * (ha * v0_ * v0_ + hc * v1_ * v1_) +              \
                 hb * (v0_ * v1_);                                            \
      val.f = vv;                                                             \
      sum += vv;                                                              \
    }
    COMP(x) COMP(y) COMP(z) COMP(w)
#undef COMP
    vals[j] = val;
  }

  // channel mean across the 4-thread quad (48 channels total)
  sum += __shfl_xor(sum, 1);
  sum += __shfl_xor(sum, 2);
  float mean = sum * (1.0f / 48.0f);

  float4* op = (float4*)(xn + (size_t)pix * NCH) + sub * 3;
#pragma unroll
  for (int j = 0; j < 3; j++) {
    float4 c4 = n[4][j];
    float4 r;
    r.x = c4.x + 0.2f * fminf(fmaxf(vals[j].x - mean, -1e8f), 1e8f);
    r.y = c4.y + 0.2f * fminf(fmaxf(vals[j].y - mean, -1e8f), 1e8f);
    r.z = c4.z + 0.2f * fminf(fmaxf(vals[j].z - mean, -1e8f), 1e8f);
    r.w = c4.w + 0.2f * fminf(fmaxf(vals[j].w - mean, -1e8f), 1e8f);
    op[j] = r;
  }
}

// ---------------------------------------------------------------------------
// Host launcher.  inputs: v (H,W,48), Dt (H,W,3), dg (H,W,1), hinv (H,W,3)
// ws layout: A[9*HW] | xbuf[HW*48]   (~60 MB)
// ping-pong: v -> out -> ws -> out -> ws -> out  (5 steps)
// ---------------------------------------------------------------------------
extern "C" void kernel_launch(void* const* d_in, const int* in_sizes, int n_in,
                              void* d_out, int out_size, void* d_ws, size_t ws_size,
                              hipStream_t stream) {
  const float* v    = (const float*)d_in[0];
  const float* Dt   = (const float*)d_in[1];
  const float* dg   = (const float*)d_in[2];
  const float* hinv = (const float*)d_in[3];
  float* out = (float*)d_out;

  float* A    = (float*)d_ws;
  float* xbuf = A + 9 * (size_t)HWPIX;

  compute_A_kernel<<<dim3(HWPIX / 256), dim3(256), 0, stream>>>(Dt, dg, A);

  const float* cur = v;
  float* nxt = out;
  for (int s = 0; s < 5; s++) {
    step_fused_kernel<<<dim3(HWPIX / 64), dim3(256), 0, stream>>>(cur, A, hinv, nxt);
    if (s == 0) {
      cur = out;
      nxt = xbuf;
    } else {
      float* t = (float*)cur;
      cur = nxt;
      nxt = t;
    }
  }
}

// Round 4
// 263.518 us; speedup vs baseline: 2.4332x; 1.0508x over previous
//
#include <hip/hip_runtime.h>
#include <math.h>

#define HH 512
#define WW 512
#define NCH 48
#define HWPIX (HH * WW)

// ---------------------------------------------------------------------------
// Kernel 1: precompute the 9 per-pixel stencil weights from Dt, with
//   - border zero-padding masks folded in (conv is SAME/zero-pad),
//   - 1/dg folded in (val = stencil(x)/dg),
//   - MSQ = 0.1 folded into the center weight (0.1*x term).
// Dt layout: (H, W, 3) with channels (a, c, b). Rolls are PERIODIC (jnp.roll).
// A stored as 9 planes of HW floats: A[k*HW + pix], A[k] multiplies
// x[h-1+k/3, w-1+k%3] (row-major patch order, no flip).
// ---------------------------------------------------------------------------
__global__ __launch_bounds__(256) void compute_A_kernel(
    const float* __restrict__ Dt, const float* __restrict__ dg,
    float* __restrict__ A) {
  int pix = blockIdx.x * blockDim.x + threadIdx.x;
  int h = pix >> 9;
  int w = pix & (WW - 1);
  int hm = (h == 0) ? HH - 1 : h - 1;
  int hp = (h == HH - 1) ? 0 : h + 1;
  int wm = (w == 0) ? WW - 1 : w - 1;
  int wp = (w == WW - 1) ? 0 : w + 1;

  float aC, cC, bC, cL, bL, cR, bR, aU, bU, aD, bD;
  float bUL, bUR, bDL, bDR;
  {
    int p;
    p = (h * WW + w) * 3;   aC = Dt[p]; cC = Dt[p + 1]; bC = Dt[p + 2];
    p = (h * WW + wm) * 3;  cL = Dt[p + 1]; bL = Dt[p + 2];
    p = (h * WW + wp) * 3;  cR = Dt[p + 1]; bR = Dt[p + 2];
    p = (hm * WW + w) * 3;  aU = Dt[p]; bU = Dt[p + 2];
    p = (hp * WW + w) * 3;  aD = Dt[p]; bD = Dt[p + 2];
    p = (hm * WW + wm) * 3; bUL = Dt[p + 2];
    p = (hm * WW + wp) * 3; bUR = Dt[p + 2];
    p = (hp * WW + wm) * 3; bDL = Dt[p + 2];
    p = (hp * WW + wp) * 3; bDR = Dt[p + 2];
  }

  float A0 = (fabsf(bDL) - bDL + fabsf(bC) - bC) * 0.25f;
  float A1 = (cL + cC - fabsf(bL) - fabsf(bC)) * 0.5f;
  float A2 = (fabsf(bUL) + bUL + fabsf(bC) + bC) * 0.25f;
  float A3 = (aD + aC - fabsf(bD) - fabsf(bC)) * 0.5f;
  float A4 = -(aD + 2.f * aC + aU) * 0.5f
             - (fabsf(bDL) - bDL + fabsf(bUL) + bUL) * 0.25f
             - (fabsf(bDR) + bDR + fabsf(bUR) - bUR) * 0.25f
             + (fabsf(bD) + fabsf(bU) + fabsf(bR) + fabsf(bL) + 2.f * fabsf(bC)) * 0.5f
             - (cR + 2.f * cC + cL) * 0.5f;
  float A5 = (aU + aC - fabsf(bU) - fabsf(bC)) * 0.5f;
  float A6 = (fabsf(bDR) + bDR + fabsf(bC) + bC) * 0.25f;
  float A7 = (cR + cC - fabsf(bR) - fabsf(bC)) * 0.5f;
  float A8 = (fabsf(bUR) - bUR + fabsf(bC) - bC) * 0.25f;

  // zero-padding of the conv: drop out-of-bounds contributions
  bool ru = (h > 0), rd = (h < HH - 1), cl = (w > 0), cr = (w < WW - 1);
  if (!(ru && cl)) A0 = 0.f;
  if (!ru)         A1 = 0.f;
  if (!(ru && cr)) A2 = 0.f;
  if (!cl)         A3 = 0.f;
  if (!cr)         A5 = 0.f;
  if (!(rd && cl)) A6 = 0.f;
  if (!rd)         A7 = 0.f;
  if (!(rd && cr)) A8 = 0.f;

  float invdg = 1.0f / dg[pix];
  A[0 * HWPIX + pix] = A0 * invdg;
  A[1 * HWPIX + pix] = A1 * invdg;
  A[2 * HWPIX + pix] = A2 * invdg;
  A[3 * HWPIX + pix] = A3 * invdg;
  A[4 * HWPIX + pix] = A4 * invdg + 0.1f;   // + MSQ*x folded into center tap
  A[5 * HWPIX + pix] = A5 * invdg;
  A[6 * HWPIX + pix] = A6 * invdg;
  A[7 * HWPIX + pix] = A7 * invdg;
  A[8 * HWPIX + pix] = A8 * invdg;
}

// ---------------------------------------------------------------------------
// Fused Euler step. 4 threads per pixel, 64 pixels per 256-thread block.
// COALESCING: thread `sub` owns INTERLEAVED float4 chunks {sub, 4+sub, 8+sub}
// (chunk = j*4+sub), so each wave-load instruction's lane addresses are
//   pix*192 + j*64 + sub*16  -> each quad consumes one full contiguous 64-B
// line; a wave-load touches exactly 16 fully-used cachelines (optimum).
// The previous consecutive mapping (sub*3+j, stride-48 lanes) touched 48
// partially-used lines per load -> 3x the L1 request cost (the R3 limiter).
// The three logsumexps (center, down=h+1, right=w+1) are computed in-register
// via 2-stage __shfl_xor butterflies over the quad — no separate lse pass.
//   val = sum_k Aeff[k]*x[nbr_k] + 0.5*(ha*v0^2 + hc*v1^2) + hb*v0*v1
//   v0 = logp[h+1,w]-logp[h,w], v1 = logp[h,w+1]-logp[h,w]  (periodic)
//   x_next = x + 0.2 * clip(val - mean_ch(val), +-1e8)
// XCD-band swizzle: 4096 blocks round-robin over 8 XCDs -> XCD k gets a
// contiguous 64-row band so stencil reuse stays within one per-XCD L2.
// ---------------------------------------------------------------------------
__global__ __launch_bounds__(256) void step_fused_kernel(
    const float* __restrict__ x, const float* __restrict__ A,
    const float* __restrict__ hinv, float* __restrict__ xn) {
  int b = blockIdx.x;
  int chunk = (b & 7) * 512 + (b >> 3);       // 64-pixel chunk index
  int sub = threadIdx.x & 3;                  // which interleaved chunk set
  int pix = chunk * 64 + (threadIdx.x >> 2);
  int h = pix >> 9;
  int w = pix & (WW - 1);
  int hm = (h == 0) ? HH - 1 : h - 1;
  int hp = (h == HH - 1) ? 0 : h + 1;
  int wm = (w == 0) ? WW - 1 : w - 1;
  int wp = (w == WW - 1) ? 0 : w + 1;

  float wt[9];
#pragma unroll
  for (int k = 0; k < 9; k++) wt[k] = A[k * HWPIX + pix];

  float ha = hinv[pix * 3 + 0];
  float hc = hinv[pix * 3 + 1];
  float hb = hinv[pix * 3 + 2];

  // neighbor base pointers (float4 granularity, no sub offset)
  const float4* p[9];
  {
    int rows[3] = {hm, h, hp};
    int cols[3] = {wm, w, wp};
#pragma unroll
    for (int r = 0; r < 3; r++)
#pragma unroll
      for (int c = 0; c < 3; c++)
        p[r * 3 + c] = (const float4*)(x + (size_t)(rows[r] * WW + cols[c]) * NCH);
  }

  // load all 9 neighbors x 3 float4 chunks (interleaved: chunk = j*4+sub)
  float4 n[9][3];
#pragma unroll
  for (int k = 0; k < 9; k++)
#pragma unroll
    for (int j = 0; j < 3; j++) n[k][j] = p[k][j * 4 + sub];

  // --- logsumexp for center (n4), down (n7), right (n5) ------------------
#define TMAX4(q) fmaxf(fmaxf(q.x, q.y), fmaxf(q.z, q.w))
#define TSUM4(q, m) (__expf(q.x - m) + __expf(q.y - m) + __expf(q.z - m) + __expf(q.w - m))
  float m4 = fmaxf(TMAX4(n[4][0]), fmaxf(TMAX4(n[4][1]), TMAX4(n[4][2])));
  float m5 = fmaxf(TMAX4(n[5][0]), fmaxf(TMAX4(n[5][1]), TMAX4(n[5][2])));
  float m7 = fmaxf(TMAX4(n[7][0]), fmaxf(TMAX4(n[7][1]), TMAX4(n[7][2])));
  m4 = fmaxf(m4, __shfl_xor(m4, 1)); m4 = fmaxf(m4, __shfl_xor(m4, 2));
  m5 = fmaxf(m5, __shfl_xor(m5, 1)); m5 = fmaxf(m5, __shfl_xor(m5, 2));
  m7 = fmaxf(m7, __shfl_xor(m7, 1)); m7 = fmaxf(m7, __shfl_xor(m7, 2));
  float s4 = TSUM4(n[4][0], m4) + TSUM4(n[4][1], m4) + TSUM4(n[4][2], m4);
  float s5 = TSUM4(n[5][0], m5) + TSUM4(n[5][1], m5) + TSUM4(n[5][2], m5);
  float s7 = TSUM4(n[7][0], m7) + TSUM4(n[7][1], m7) + TSUM4(n[7][2], m7);
  s4 += __shfl_xor(s4, 1); s4 += __shfl_xor(s4, 2);
  s5 += __shfl_xor(s5, 1); s5 += __shfl_xor(s5, 2);
  s7 += __shfl_xor(s7, 1); s7 += __shfl_xor(s7, 2);
  float lse4 = m4 + __logf(s4);
  float lse5 = m5 + __logf(s5);
  float lse7 = m7 + __logf(s7);
  float dld = lse4 - lse7;   // lse[h,w] - lse[h+1,w]
  float dlr = lse4 - lse5;   // lse[h,w] - lse[h,w+1]
#undef TMAX4
#undef TSUM4

  // --- stencil + quadratic form over this thread's 12 channels ------------
  float4 vals[3];
  float sum = 0.f;
#pragma unroll
  for (int j = 0; j < 3; j++) {
    float4 val;
#define COMP(f)                                                               \
    {                                                                         \
      float s_ = wt[0] * n[0][j].f + wt[1] * n[1][j].f + wt[2] * n[2][j].f +  \
                 wt[3] * n[3][j].f + wt[4] * n[4][j].f + wt[5] * n[5][j].f +  \
                 wt[6] * n[6][j].f + wt[7] * n[7][j].f + wt[8] * n[8][j].f;   \
      float v0_ = n[7][j].f - n[4][j].f + dld;                                \
      float v1_ = n[5][j].f - n[4][j].f + dlr;                                \
      float vv = s_ + 0.5f * (ha * v0_ * v0_ + hc * v1_ * v1_) +              \
                 hb * (v0_ * v1_);                                            \
      val.f = vv;                                                             \
      sum += vv;                                                              \
    }
    COMP(x) COMP(y) COMP(z) COMP(w)
#undef COMP
    vals[j] = val;
  }

  // channel mean across the 4-thread quad (48 channels total)
  sum += __shfl_xor(sum, 1);
  sum += __shfl_xor(sum, 2);
  float mean = sum * (1.0f / 48.0f);

  float4* op = (float4*)(xn + (size_t)pix * NCH);
#pragma unroll
  for (int j = 0; j < 3; j++) {
    float4 c4 = n[4][j];
    float4 r;
    r.x = c4.x + 0.2f * fminf(fmaxf(vals[j].x - mean, -1e8f), 1e8f);
    r.y = c4.y + 0.2f * fminf(fmaxf(vals[j].y - mean, -1e8f), 1e8f);
    r.z = c4.z + 0.2f * fminf(fmaxf(vals[j].z - mean, -1e8f), 1e8f);
    r.w = c4.w + 0.2f * fminf(fmaxf(vals[j].w - mean, -1e8f), 1e8f);
    op[j * 4 + sub] = r;
  }
}

// ---------------------------------------------------------------------------
// Host launcher.  inputs: v (H,W,48), Dt (H,W,3), dg (H,W,1), hinv (H,W,3)
// ws layout: A[9*HW] | xbuf[HW*48]   (~60 MB)
// ping-pong: v -> out -> ws -> out -> ws -> out  (5 steps)
// ---------------------------------------------------------------------------
extern "C" void kernel_launch(void* const* d_in, const int* in_sizes, int n_in,
                              void* d_out, int out_size, void* d_ws, size_t ws_size,
                              hipStream_t stream) {
  const float* v    = (const float*)d_in[0];
  const float* Dt   = (const float*)d_in[1];
  const float* dg   = (const float*)d_in[2];
  const float* hinv = (const float*)d_in[3];
  float* out = (float*)d_out;

  float* A    = (float*)d_ws;
  float* xbuf = A + 9 * (size_t)HWPIX;

  compute_A_kernel<<<dim3(HWPIX / 256), dim3(256), 0, stream>>>(Dt, dg, A);

  const float* cur = v;
  float* nxt = out;
  for (int s = 0; s < 5; s++) {
    step_fused_kernel<<<dim3(HWPIX / 64), dim3(256), 0, stream>>>(cur, A, hinv, nxt);
    if (s == 0) {
      cur = out;
      nxt = xbuf;
    } else {
      float* t = (float*)cur;
      cur = nxt;
      nxt = t;
    }
  }
}

// Round 5
// 253.842 us; speedup vs baseline: 2.5260x; 1.0381x over previous
//
#include <hip/hip_runtime.h>
#include <math.h>

#define HH 512
#define WW 512
#define NCH 48
#define HWPIX (HH * WW)

#define TILE 8           // 8x8 pixel tile per block
#define HALO 10          // tile + 1-px halo ring
#define PSTRIDE 13       // float4 slots per pixel in LDS (12 + 1 pad: breaks
                         // the 48-word bank resonance; 52 words % 32 = 20)

// ---------------------------------------------------------------------------
// Kernel 1: precompute the 9 per-pixel stencil weights from Dt, with
//   - border zero-padding masks folded in (conv is SAME/zero-pad),
//   - 1/dg folded in, MSQ=0.1 folded into the center weight.
// Dt layout: (H, W, 3) = (a, c, b); rolls are PERIODIC (jnp.roll).
// A stored as 9 planes of HW floats: A[k*HW + pix]; A[k] multiplies
// x[h-1+k/3, w-1+k%3] (row-major patch order, no flip).
// ---------------------------------------------------------------------------
__global__ __launch_bounds__(256) void compute_A_kernel(
    const float* __restrict__ Dt, const float* __restrict__ dg,
    float* __restrict__ A) {
  int pix = blockIdx.x * blockDim.x + threadIdx.x;
  int h = pix >> 9;
  int w = pix & (WW - 1);
  int hm = (h == 0) ? HH - 1 : h - 1;
  int hp = (h == HH - 1) ? 0 : h + 1;
  int wm = (w == 0) ? WW - 1 : w - 1;
  int wp = (w == WW - 1) ? 0 : w + 1;

  float aC, cC, bC, cL, bL, cR, bR, aU, bU, aD, bD;
  float bUL, bUR, bDL, bDR;
  {
    int p;
    p = (h * WW + w) * 3;   aC = Dt[p]; cC = Dt[p + 1]; bC = Dt[p + 2];
    p = (h * WW + wm) * 3;  cL = Dt[p + 1]; bL = Dt[p + 2];
    p = (h * WW + wp) * 3;  cR = Dt[p + 1]; bR = Dt[p + 2];
    p = (hm * WW + w) * 3;  aU = Dt[p]; bU = Dt[p + 2];
    p = (hp * WW + w) * 3;  aD = Dt[p]; bD = Dt[p + 2];
    p = (hm * WW + wm) * 3; bUL = Dt[p + 2];
    p = (hm * WW + wp) * 3; bUR = Dt[p + 2];
    p = (hp * WW + wm) * 3; bDL = Dt[p + 2];
    p = (hp * WW + wp) * 3; bDR = Dt[p + 2];
  }

  float A0 = (fabsf(bDL) - bDL + fabsf(bC) - bC) * 0.25f;
  float A1 = (cL + cC - fabsf(bL) - fabsf(bC)) * 0.5f;
  float A2 = (fabsf(bUL) + bUL + fabsf(bC) + bC) * 0.25f;
  float A3 = (aD + aC - fabsf(bD) - fabsf(bC)) * 0.5f;
  float A4 = -(aD + 2.f * aC + aU) * 0.5f
             - (fabsf(bDL) - bDL + fabsf(bUL) + bUL) * 0.25f
             - (fabsf(bDR) + bDR + fabsf(bUR) - bUR) * 0.25f
             + (fabsf(bD) + fabsf(bU) + fabsf(bR) + fabsf(bL) + 2.f * fabsf(bC)) * 0.5f
             - (cR + 2.f * cC + cL) * 0.5f;
  float A5 = (aU + aC - fabsf(bU) - fabsf(bC)) * 0.5f;
  float A6 = (fabsf(bDR) + bDR + fabsf(bC) + bC) * 0.25f;
  float A7 = (cR + cC - fabsf(bR) - fabsf(bC)) * 0.5f;
  float A8 = (fabsf(bUR) - bUR + fabsf(bC) - bC) * 0.25f;

  bool ru = (h > 0), rd = (h < HH - 1), cl = (w > 0), cr = (w < WW - 1);
  if (!(ru && cl)) A0 = 0.f;
  if (!ru)         A1 = 0.f;
  if (!(ru && cr)) A2 = 0.f;
  if (!cl)         A3 = 0.f;
  if (!cr)         A5 = 0.f;
  if (!(rd && cl)) A6 = 0.f;
  if (!rd)         A7 = 0.f;
  if (!(rd && cr)) A8 = 0.f;

  float invdg = 1.0f / dg[pix];
  A[0 * HWPIX + pix] = A0 * invdg;
  A[1 * HWPIX + pix] = A1 * invdg;
  A[2 * HWPIX + pix] = A2 * invdg;
  A[3 * HWPIX + pix] = A3 * invdg;
  A[4 * HWPIX + pix] = A4 * invdg + 0.1f;
  A[5 * HWPIX + pix] = A5 * invdg;
  A[6 * HWPIX + pix] = A6 * invdg;
  A[7 * HWPIX + pix] = A7 * invdg;
  A[8 * HWPIX + pix] = A8 * invdg;
}

// ---------------------------------------------------------------------------
// Fused Euler step with 2D LDS tiling.
// Block = 8x8 pixel tile, 4 threads/pixel (quad owns interleaved float4
// chunks {sub, 4+sub, 8+sub}).  Phase 1 stages the 10x10 halo tile (periodic
// wrap; the conv's zero-padding lives in the masked A weights) into LDS with
// 1200 independent coalesced global loads. Phase 2: all 9-neighbor reads are
// LDS hits; the three logsumexps (center, down, right) come from quad
// __shfl_xor butterflies; channel mean likewise.
//   val = sum_k Aeff[k]*x[nbr_k] + 0.5*(ha*v0^2 + hc*v1^2) + hb*v0*v1
//   x_next = x + 0.2 * clip(val - mean_ch(val), +-1e8)
// XCD-band swizzle: XCD k (= b%8) gets tile rows [8k, 8k+8) -> a 64-pixel-row
// band per XCD so vertical halo reuse stays inside one per-XCD L2.
// ---------------------------------------------------------------------------
__global__ __launch_bounds__(256, 4) void step_fused_kernel(
    const float* __restrict__ x, const float* __restrict__ A,
    const float* __restrict__ hinv, float* __restrict__ xn) {
  __shared__ float4 tile[HALO * HALO * PSTRIDE];   // 20,800 B

  int b = blockIdx.x;
  int tile_id = (b & 7) * 512 + (b >> 3);          // 4096 tiles, 64x64 grid
  int th0 = (tile_id >> 6) * TILE;
  int tw0 = (tile_id & 63) * TILE;

  // ---- Phase 1: stage 10x10 halo x 12 chunks into LDS -------------------
  const float4* xb = (const float4*)x;
  for (int idx = threadIdx.x; idx < HALO * HALO * 12; idx += 256) {
    int p = idx / 12;
    int ch = idx - p * 12;
    int r = p / 10;
    int c = p - r * 10;
    int gh = (th0 + r - 1) & (HH - 1);             // periodic wrap
    int gw = (tw0 + c - 1) & (WW - 1);
    tile[p * PSTRIDE + ch] = xb[(size_t)(gh * WW + gw) * 12 + ch];
  }
  __syncthreads();

  // ---- Phase 2: per-pixel compute ---------------------------------------
  int sub = threadIdx.x & 3;                       // interleaved chunk set
  int pidx = threadIdx.x >> 2;                     // 0..63 pixel in tile
  int pr = pidx >> 3, pc = pidx & 7;
  int h = th0 + pr, w = tw0 + pc;
  int pix = h * WW + w;

  float wt[9];
#pragma unroll
  for (int k = 0; k < 9; k++) wt[k] = A[k * HWPIX + pix];
  float ha = hinv[pix * 3 + 0];
  float hc = hinv[pix * 3 + 1];
  float hb = hinv[pix * 3 + 2];

  // LDS float4-offsets of the 9 neighbors (patch order k = (dr+1)*3+(dc+1))
  int tc = (pr + 1) * HALO + (pc + 1);
  int toff[9];
#pragma unroll
  for (int dr = -1; dr <= 1; dr++)
#pragma unroll
    for (int dc = -1; dc <= 1; dc++)
      toff[(dr + 1) * 3 + (dc + 1)] = (tc + dr * HALO + dc) * PSTRIDE;

  // center / right / down chunk vectors (kept live; reused in stencil)
  float4 C[3], R[3], D[3];
#pragma unroll
  for (int j = 0; j < 3; j++) {
    int ch = j * 4 + sub;
    C[j] = tile[toff[4] + ch];
    R[j] = tile[toff[5] + ch];
    D[j] = tile[toff[7] + ch];
  }

  // --- logsumexp for center, right (w+1), down (h+1) via quad butterflies
#define TMAX4(q) fmaxf(fmaxf(q.x, q.y), fmaxf(q.z, q.w))
#define TSUM4(q, m) (__expf(q.x - m) + __expf(q.y - m) + __expf(q.z - m) + __expf(q.w - m))
  float m4 = fmaxf(TMAX4(C[0]), fmaxf(TMAX4(C[1]), TMAX4(C[2])));
  float m5 = fmaxf(TMAX4(R[0]), fmaxf(TMAX4(R[1]), TMAX4(R[2])));
  float m7 = fmaxf(TMAX4(D[0]), fmaxf(TMAX4(D[1]), TMAX4(D[2])));
  m4 = fmaxf(m4, __shfl_xor(m4, 1)); m4 = fmaxf(m4, __shfl_xor(m4, 2));
  m5 = fmaxf(m5, __shfl_xor(m5, 1)); m5 = fmaxf(m5, __shfl_xor(m5, 2));
  m7 = fmaxf(m7, __shfl_xor(m7, 1)); m7 = fmaxf(m7, __shfl_xor(m7, 2));
  float s4 = TSUM4(C[0], m4) + TSUM4(C[1], m4) + TSUM4(C[2], m4);
  float s5 = TSUM4(R[0], m5) + TSUM4(R[1], m5) + TSUM4(R[2], m5);
  float s7 = TSUM4(D[0], m7) + TSUM4(D[1], m7) + TSUM4(D[2], m7);
  s4 += __shfl_xor(s4, 1); s4 += __shfl_xor(s4, 2);
  s5 += __shfl_xor(s5, 1); s5 += __shfl_xor(s5, 2);
  s7 += __shfl_xor(s7, 1); s7 += __shfl_xor(s7, 2);
  float lse4 = m4 + __logf(s4);
  float lse5 = m5 + __logf(s5);
  float lse7 = m7 + __logf(s7);
  float dld = lse4 - lse7;   // lse[h,w] - lse[h+1,w]
  float dlr = lse4 - lse5;   // lse[h,w] - lse[h,w+1]
#undef TMAX4
#undef TSUM4

  // --- stencil + quadratic form over this thread's 12 channels ------------
  float4 vals[3];
  float sum = 0.f;
#pragma unroll
  for (int j = 0; j < 3; j++) {
    int ch = j * 4 + sub;
    float4 q0 = tile[toff[0] + ch];
    float4 q1 = tile[toff[1] + ch];
    float4 q2 = tile[toff[2] + ch];
    float4 q3 = tile[toff[3] + ch];
    float4 q4 = C[j];
    float4 q5 = R[j];
    float4 q6 = tile[toff[6] + ch];
    float4 q7 = D[j];
    float4 q8 = tile[toff[8] + ch];
    float4 val;
#define COMP(f)                                                               \
    {                                                                         \
      float s_ = wt[0] * q0.f + wt[1] * q1.f + wt[2] * q2.f + wt[3] * q3.f +  \
                 wt[4] * q4.f + wt[5] * q5.f + wt[6] * q6.f + wt[7] * q7.f +  \
                 wt[8] * q8.f;                                                \
      float v0_ = q7.f - q4.f + dld;                                          \
      float v1_ = q5.f - q4.f + dlr;                                          \
      float vv = s_ + 0.5f * (ha * v0_ * v0_ + hc * v1_ * v1_) +              \
                 hb * (v0_ * v1_);                                            \
      val.f = vv;                                                             \
      sum += vv;                                                              \
    }
    COMP(x) COMP(y) COMP(z) COMP(w)
#undef COMP
    vals[j] = val;
  }

  // channel mean across the 4-thread quad (48 channels total)
  sum += __shfl_xor(sum, 1);
  sum += __shfl_xor(sum, 2);
  float mean = sum * (1.0f / 48.0f);

  float4* op = (float4*)(xn + (size_t)pix * NCH);
#pragma unroll
  for (int j = 0; j < 3; j++) {
    float4 c4 = C[j];
    float4 r;
    r.x = c4.x + 0.2f * fminf(fmaxf(vals[j].x - mean, -1e8f), 1e8f);
    r.y = c4.y + 0.2f * fminf(fmaxf(vals[j].y - mean, -1e8f), 1e8f);
    r.z = c4.z + 0.2f * fminf(fmaxf(vals[j].z - mean, -1e8f), 1e8f);
    r.w = c4.w + 0.2f * fminf(fmaxf(vals[j].w - mean, -1e8f), 1e8f);
    op[j * 4 + sub] = r;
  }
}

// ---------------------------------------------------------------------------
// Host launcher.  inputs: v (H,W,48), Dt (H,W,3), dg (H,W,1), hinv (H,W,3)
// ws layout: A[9*HW] | xbuf[HW*48]   (~60 MB)
// ping-pong: v -> out -> ws -> out -> ws -> out  (5 steps)
// ---------------------------------------------------------------------------
extern "C" void kernel_launch(void* const* d_in, const int* in_sizes, int n_in,
                              void* d_out, int out_size, void* d_ws, size_t ws_size,
                              hipStream_t stream) {
  const float* v    = (const float*)d_in[0];
  const float* Dt   = (const float*)d_in[1];
  const float* dg   = (const float*)d_in[2];
  const float* hinv = (const float*)d_in[3];
  float* out = (float*)d_out;

  float* A    = (float*)d_ws;
  float* xbuf = A + 9 * (size_t)HWPIX;

  compute_A_kernel<<<dim3(HWPIX / 256), dim3(256), 0, stream>>>(Dt, dg, A);

  const float* cur = v;
  float* nxt = out;
  for (int s = 0; s < 5; s++) {
    step_fused_kernel<<<dim3(HWPIX / 64), dim3(256), 0, stream>>>(cur, A, hinv, nxt);
    if (s == 0) {
      cur = out;
      nxt = xbuf;
    } else {
      float* t = (float*)cur;
      cur = nxt;
      nxt = t;
    }
  }
}

// Round 6
// 214.641 us; speedup vs baseline: 2.9873x; 1.1826x over previous
//
#include <hip/hip_runtime.h>
#include <math.h>

#define HH 512
#define WW 512
#define NCH 48
#define HWPIX (HH * WW)

#define TW 16            // tile width (pixels)
#define TH 8             // tile height
#define HW_HALO 18       // TW + 2
#define HH_HALO 10       // TH + 2
#define NHALO (HW_HALO * HH_HALO)   // 180 halo pixels
#define PSTRIDE 13       // float4 slots per halo pixel (12 + 1 pad)

// ---------------------------------------------------------------------------
// Kernel 1: precompute the 9 per-pixel stencil weights from Dt, with
//   - border zero-padding masks folded in (conv is SAME/zero-pad),
//   - 1/dg folded in, MSQ=0.1 folded into the center weight.
// Dt layout: (H, W, 3) = (a, c, b); rolls are PERIODIC (jnp.roll).
// A stored as 9 planes of HW floats: A[k*HW + pix]; A[k] multiplies
// x[h-1+k/3, w-1+k%3] (row-major patch order, no flip).
// ---------------------------------------------------------------------------
__global__ __launch_bounds__(256) void compute_A_kernel(
    const float* __restrict__ Dt, const float* __restrict__ dg,
    float* __restrict__ A) {
  int pix = blockIdx.x * blockDim.x + threadIdx.x;
  int h = pix >> 9;
  int w = pix & (WW - 1);
  int hm = (h == 0) ? HH - 1 : h - 1;
  int hp = (h == HH - 1) ? 0 : h + 1;
  int wm = (w == 0) ? WW - 1 : w - 1;
  int wp = (w == WW - 1) ? 0 : w + 1;

  float aC, cC, bC, cL, bL, cR, bR, aU, bU, aD, bD;
  float bUL, bUR, bDL, bDR;
  {
    int p;
    p = (h * WW + w) * 3;   aC = Dt[p]; cC = Dt[p + 1]; bC = Dt[p + 2];
    p = (h * WW + wm) * 3;  cL = Dt[p + 1]; bL = Dt[p + 2];
    p = (h * WW + wp) * 3;  cR = Dt[p + 1]; bR = Dt[p + 2];
    p = (hm * WW + w) * 3;  aU = Dt[p]; bU = Dt[p + 2];
    p = (hp * WW + w) * 3;  aD = Dt[p]; bD = Dt[p + 2];
    p = (hm * WW + wm) * 3; bUL = Dt[p + 2];
    p = (hm * WW + wp) * 3; bUR = Dt[p + 2];
    p = (hp * WW + wm) * 3; bDL = Dt[p + 2];
    p = (hp * WW + wp) * 3; bDR = Dt[p + 2];
  }

  float A0 = (fabsf(bDL) - bDL + fabsf(bC) - bC) * 0.25f;
  float A1 = (cL + cC - fabsf(bL) - fabsf(bC)) * 0.5f;
  float A2 = (fabsf(bUL) + bUL + fabsf(bC) + bC) * 0.25f;
  float A3 = (aD + aC - fabsf(bD) - fabsf(bC)) * 0.5f;
  float A4 = -(aD + 2.f * aC + aU) * 0.5f
             - (fabsf(bDL) - bDL + fabsf(bUL) + bUL) * 0.25f
             - (fabsf(bDR) + bDR + fabsf(bUR) - bUR) * 0.25f
             + (fabsf(bD) + fabsf(bU) + fabsf(bR) + fabsf(bL) + 2.f * fabsf(bC)) * 0.5f
             - (cR + 2.f * cC + cL) * 0.5f;
  float A5 = (aU + aC - fabsf(bU) - fabsf(bC)) * 0.5f;
  float A6 = (fabsf(bDR) + bDR + fabsf(bC) + bC) * 0.25f;
  float A7 = (cR + cC - fabsf(bR) - fabsf(bC)) * 0.5f;
  float A8 = (fabsf(bUR) - bUR + fabsf(bC) - bC) * 0.25f;

  bool ru = (h > 0), rd = (h < HH - 1), cl = (w > 0), cr = (w < WW - 1);
  if (!(ru && cl)) A0 = 0.f;
  if (!ru)         A1 = 0.f;
  if (!(ru && cr)) A2 = 0.f;
  if (!cl)         A3 = 0.f;
  if (!cr)         A5 = 0.f;
  if (!(rd && cl)) A6 = 0.f;
  if (!rd)         A7 = 0.f;
  if (!(rd && cr)) A8 = 0.f;

  float invdg = 1.0f / dg[pix];
  A[0 * HWPIX + pix] = A0 * invdg;
  A[1 * HWPIX + pix] = A1 * invdg;
  A[2 * HWPIX + pix] = A2 * invdg;
  A[3 * HWPIX + pix] = A3 * invdg;
  A[4 * HWPIX + pix] = A4 * invdg + 0.1f;
  A[5 * HWPIX + pix] = A5 * invdg;
  A[6 * HWPIX + pix] = A6 * invdg;
  A[7 * HWPIX + pix] = A7 * invdg;
  A[8 * HWPIX + pix] = A8 * invdg;
}

// ---------------------------------------------------------------------------
// Fused Euler step, 16x8 tile, 2-pixel register blocking, lse-once staging.
// Phase 1: threads 0..179 each stage one halo pixel's 12 float4 from global
//   (periodic wrap) into LDS AND compute its 48-channel logsumexp in-register
//   (each lse computed exactly once — R5 computed each 3x via butterflies).
// Phase 2: quad (4 threads, sub = interleaved chunk j*4+sub) handles a
//   horizontally-adjacent pixel PAIR: 3x4 LDS patch per chunk serves both
//   pixels' 3x3 stencils (18 b128/pixel vs 27 in R5).
//   val = sum_k Aeff[k]*x[nbr_k] + 0.5*(ha*v0^2 + hc*v1^2) + hb*v0*v1
//   v0 = logp[h+1,w]-logp[h,w], v1 = logp[h,w+1]-logp[h,w]  (periodic)
//   x_next = x + 0.2 * clip(val - mean_ch(val), +-1e8)
// XCD-band swizzle: XCD k (= b%8) gets tile rows [8k,8k+8) = pixel rows
// [64k, 64k+64), keeping vertical halo reuse inside one per-XCD L2.
// ---------------------------------------------------------------------------
__global__ __launch_bounds__(256, 4) void step_fused_kernel(
    const float* __restrict__ x, const float* __restrict__ A,
    const float* __restrict__ hinv, float* __restrict__ xn) {
  __shared__ float4 tile[NHALO * PSTRIDE];   // 180*13*16 = 37,440 B
  __shared__ float lse_s[NHALO];             // + 720 B

  int b = blockIdx.x;
  int tile_id = (b & 7) * 256 + (b >> 3);    // 2048 tiles, 64 rows x 32 cols
  int th0 = (tile_id >> 5) * TH;
  int tw0 = (tile_id & 31) * TW;

  // ---- Phase 1: stage halo + per-pixel lse (once) -----------------------
  int t = threadIdx.x;
  if (t < NHALO) {
    int r = t / HW_HALO;
    int c = t - r * HW_HALO;
    int gh = (th0 + r - 1) & (HH - 1);       // periodic wrap
    int gw = (tw0 + c - 1) & (WW - 1);
    const float4* src = (const float4*)x + (size_t)(gh * WW + gw) * 12;
    float4 v[12];
    float m = -INFINITY;
#pragma unroll
    for (int i = 0; i < 12; i++) {
      v[i] = src[i];
      m = fmaxf(m, fmaxf(fmaxf(v[i].x, v[i].y), fmaxf(v[i].z, v[i].w)));
    }
    float s = 0.f;
#pragma unroll
    for (int i = 0; i < 12; i++) {
      s += __expf(v[i].x - m) + __expf(v[i].y - m) +
           __expf(v[i].z - m) + __expf(v[i].w - m);
      tile[t * PSTRIDE + i] = v[i];
    }
    lse_s[t] = m + __logf(s);
  }
  __syncthreads();

  // ---- Phase 2: pixel-pair compute --------------------------------------
  int sub = t & 3;                            // interleaved chunk set
  int pair = t >> 2;                          // 0..63
  int pr = pair >> 3;                         // tile row 0..7
  int pc0 = (pair & 7) * 2;                   // even tile col 0..14

  int pix0 = (th0 + pr) * WW + (tw0 + pc0);
  int pix1 = pix0 + 1;

  float wt0[9], wt1[9];
#pragma unroll
  for (int k = 0; k < 9; k++) {
    wt0[k] = A[k * HWPIX + pix0];
    wt1[k] = A[k * HWPIX + pix1];
  }
  float ha0 = hinv[pix0 * 3 + 0], hc0 = hinv[pix0 * 3 + 1], hb0 = hinv[pix0 * 3 + 2];
  float ha1 = hinv[pix1 * 3 + 0], hc1 = hinv[pix1 * 3 + 1], hb1 = hinv[pix1 * 3 + 2];

  // lse taps (halo coords: center of px0 = (pr+1, pc0+1))
  int lc0 = (pr + 1) * HW_HALO + (pc0 + 1);
  float l0C = lse_s[lc0];
  float l0R = lse_s[lc0 + 1];                 // = l1C
  float l1R = lse_s[lc0 + 2];
  float l0D = lse_s[lc0 + HW_HALO];
  float l1D = lse_s[lc0 + HW_HALO + 1];
  float dld0 = l0C - l0D, dlr0 = l0C - l0R;
  float dld1 = l0R - l1D, dlr1 = l0R - l1R;

  // LDS float4-offsets of the 3x4 patch (rows pr..pr+2, cols pc0..pc0+3)
  int poff[3][4];
#pragma unroll
  for (int dr = 0; dr < 3; dr++)
#pragma unroll
    for (int dc = 0; dc < 4; dc++)
      poff[dr][dc] = ((pr + dr) * HW_HALO + pc0 + dc) * PSTRIDE;

  float4 vals0[3], vals1[3];
  float sum0 = 0.f, sum1 = 0.f;
#pragma unroll
  for (int j = 0; j < 3; j++) {
    int ch = j * 4 + sub;
    float4 q[3][4];
#pragma unroll
    for (int dr = 0; dr < 3; dr++)
#pragma unroll
      for (int dc = 0; dc < 4; dc++) q[dr][dc] = tile[poff[dr][dc] + ch];

    float4 val0, val1;
#define COMP(f)                                                                \
    {                                                                          \
      float s0_ = wt0[0] * q[0][0].f + wt0[1] * q[0][1].f + wt0[2] * q[0][2].f \
                + wt0[3] * q[1][0].f + wt0[4] * q[1][1].f + wt0[5] * q[1][2].f \
                + wt0[6] * q[2][0].f + wt0[7] * q[2][1].f + wt0[8] * q[2][2].f;\
      float v00 = q[2][1].f - q[1][1].f + dld0;                                \
      float v10 = q[1][2].f - q[1][1].f + dlr0;                                \
      float vv0 = s0_ + 0.5f * (ha0 * v00 * v00 + hc0 * v10 * v10) +           \
                  hb0 * (v00 * v10);                                           \
      val0.f = vv0; sum0 += vv0;                                               \
      float s1_ = wt1[0] * q[0][1].f + wt1[1] * q[0][2].f + wt1[2] * q[0][3].f \
                + wt1[3] * q[1][1].f + wt1[4] * q[1][2].f + wt1[5] * q[1][3].f \
                + wt1[6] * q[2][1].f + wt1[7] * q[2][2].f + wt1[8] * q[2][3].f;\
      float v01 = q[2][2].f - q[1][2].f + dld1;                                \
      float v11 = q[1][3].f - q[1][2].f + dlr1;                                \
      float vv1 = s1_ + 0.5f * (ha1 * v01 * v01 + hc1 * v11 * v11) +           \
                  hb1 * (v01 * v11);                                           \
      val1.f = vv1; sum1 += vv1;                                               \
    }
    COMP(x) COMP(y) COMP(z) COMP(w)
#undef COMP
    vals0[j] = val0;
    vals1[j] = val1;
  }

  // channel mean across the 4-thread quad (48 channels per pixel)
  sum0 += __shfl_xor(sum0, 1); sum0 += __shfl_xor(sum0, 2);
  sum1 += __shfl_xor(sum1, 1); sum1 += __shfl_xor(sum1, 2);
  float mean0 = sum0 * (1.0f / 48.0f);
  float mean1 = sum1 * (1.0f / 48.0f);

  // centers re-read from LDS (saves 24 VGPRs vs holding them live)
  int cen0 = lc0 * PSTRIDE;                   // px0 center halo offset
  float4* op0 = (float4*)(xn + (size_t)pix0 * NCH);
  float4* op1 = op0 + 12;
#pragma unroll
  for (int j = 0; j < 3; j++) {
    int ch = j * 4 + sub;
    float4 c0 = tile[cen0 + ch];
    float4 c1 = tile[cen0 + PSTRIDE + ch];
    float4 r0, r1;
    r0.x = c0.x + 0.2f * fminf(fmaxf(vals0[j].x - mean0, -1e8f), 1e8f);
    r0.y = c0.y + 0.2f * fminf(fmaxf(vals0[j].y - mean0, -1e8f), 1e8f);
    r0.z = c0.z + 0.2f * fminf(fmaxf(vals0[j].z - mean0, -1e8f), 1e8f);
    r0.w = c0.w + 0.2f * fminf(fmaxf(vals0[j].w - mean0, -1e8f), 1e8f);
    r1.x = c1.x + 0.2f * fminf(fmaxf(vals1[j].x - mean1, -1e8f), 1e8f);
    r1.y = c1.y + 0.2f * fminf(fmaxf(vals1[j].y - mean1, -1e8f), 1e8f);
    r1.z = c1.z + 0.2f * fminf(fmaxf(vals1[j].z - mean1, -1e8f), 1e8f);
    r1.w = c1.w + 0.2f * fminf(fmaxf(vals1[j].w - mean1, -1e8f), 1e8f);
    op0[ch] = r0;
    op1[ch] = r1;
  }
}

// ---------------------------------------------------------------------------
// Host launcher.  inputs: v (H,W,48), Dt (H,W,3), dg (H,W,1), hinv (H,W,3)
// ws layout: A[9*HW] | xbuf[HW*48]   (~60 MB)
// ping-pong: v -> out -> ws -> out -> ws -> out  (5 steps)
// ---------------------------------------------------------------------------
extern "C" void kernel_launch(void* const* d_in, const int* in_sizes, int n_in,
                              void* d_out, int out_size, void* d_ws, size_t ws_size,
                              hipStream_t stream) {
  const float* v    = (const float*)d_in[0];
  const float* Dt   = (const float*)d_in[1];
  const float* dg   = (const float*)d_in[2];
  const float* hinv = (const float*)d_in[3];
  float* out = (float*)d_out;

  float* A    = (float*)d_ws;
  float* xbuf = A + 9 * (size_t)HWPIX;

  compute_A_kernel<<<dim3(HWPIX / 256), dim3(256), 0, stream>>>(Dt, dg, A);

  const float* cur = v;
  float* nxt = out;
  for (int s = 0; s < 5; s++) {
    step_fused_kernel<<<dim3(HWPIX / 128), dim3(256), 0, stream>>>(cur, A, hinv, nxt);
    if (s == 0) {
      cur = out;
      nxt = xbuf;
    } else {
      float* t = (float*)cur;
      cur = nxt;
      nxt = t;
    }
  }
}